// Round 14
// baseline (360.310 us; speedup 1.0000x reference)
//
#include <hip/hip_runtime.h>
#include <math.h>

// ChamferDistanceL1: B=8, N=M=4096, fp32.
// R20: ALGORITHMIC -- sorted z-band pruning. R13-R19 established: brute
// force is pinned at fill ~41.5 (unconditional harness poison of d_ws) +
// fused ~27 (VALUBusy 95%, issue-bound) -> total 81-87. Only lever left is
// computing fewer pairs. L1 d >= |dz| and fp32-RN addition of non-negatives
// is monotone, so z-band termination is EXACT (skipped candidates have
// d >= dz >= dmin >= true min; returned min is bit-identical).
//  - sort_kernel: per (batch, array) bitonic sort by z in LDS (48KB),
//    SoA planes -> d_ws (~786KB; ws is poisoned anyway).
//  - scan_kernel: stage sorted db in LDS; 4 lanes/query (2 down / 2 up,
//    stride 2), binary search + outward band scan, terminate on
//    dz >= dmin. Cross-lane combine ONCE after the loop (2 shfl_xor;
//    the R12/R14/R15 lesson), block-sum, 1 atomicAdd. No y-table, no
//    reduce kernel. Distance computed (|dc0|+|dc1|)+|dc2| matching the
//    reference's coordinate order.
// Expected band ~few hundred/4096 -> sort ~6us + scan ~10us replaces 27+3.5.
// Predict total ~62-70. Falsifiers: absmax!=0 -> revert R14; scan in top-5
// -> pruning underperformed, add pair dmin-sharing.

#define XOFF 0
#define YOFF (8 * 3 * 4096)  // 98304 floats
#define WS_NEED ((size_t)(2 * 8 * 3 * 4096) * 4)

__global__ void zero_out_kernel(float* __restrict__ out) { out[0] = 0.0f; }

// ---- sort: per (which, batch) bitonic sort 4096 points by c2 (z) ----
__global__ __launch_bounds__(1024) void sort_kernel(
    const float* __restrict__ x, const float* __restrict__ y,
    float* __restrict__ ws, float* __restrict__ out) {
  const int which = blockIdx.x;  // 0: x, 1: y
  const int b = blockIdx.y;
  const float* __restrict__ src = (which ? y : x) + (size_t)b * 4096 * 3;
  float* __restrict__ dst = ws + (which ? YOFF : XOFF) + b * 3 * 4096;
  __shared__ float k0[4096], k1[4096], k2[4096];  // 48 KB
  const int t = threadIdx.x;

  if (which == 0 && b == 0 && t == 0) out[0] = 0.0f;  // scan runs after us

  for (int p = t; p < 4096; p += 1024) {
    k0[p] = src[3 * p + 0];
    k1[p] = src[3 * p + 1];
    k2[p] = src[3 * p + 2];
  }
  for (int k = 2; k <= 4096; k <<= 1) {
    for (int j = k >> 1; j > 0; j >>= 1) {
      __syncthreads();
      for (int i = t; i < 4096; i += 1024) {
        const int l = i ^ j;
        if (l > i) {
          const bool asc = ((i & k) == 0);
          const float zi = k2[i], zl = k2[l];
          if ((zi > zl) == asc) {
            k2[i] = zl; k2[l] = zi;
            const float a0 = k0[i], b0 = k0[l];
            k0[i] = b0; k0[l] = a0;
            const float a1 = k1[i], b1 = k1[l];
            k1[i] = b1; k1[l] = a1;
          }
        }
      }
    }
  }
  __syncthreads();
  for (int p = t; p < 4096; p += 1024) {
    dst[p] = k0[p];
    dst[4096 + p] = k1[p];
    dst[8192 + p] = k2[p];
  }
}

// ---- scan: banded exact NN per query; 4 lanes/query; sum -> atomicAdd ----
__global__ __launch_bounds__(512) void scan_kernel(
    const float* __restrict__ ws, float* __restrict__ out, float sx,
    float sy) {
  const int tile = blockIdx.x;  // 0..31 (128 queries each)
  const int b = blockIdx.y;
  const int dir = blockIdx.z;  // 0: q=x db=y, 1: q=y db=x
  const float* __restrict__ Q = ws + (dir ? YOFF : XOFF) + b * 12288;
  const float* __restrict__ D = ws + (dir ? XOFF : YOFF) + b * 12288;
  const float scale = dir ? sy : sx;
  __shared__ float d0[4096], d1[4096], d2[4096];  // 48 KB sorted db
  const int t = threadIdx.x;

  for (int p = t; p < 4096; p += 512) {
    d0[p] = D[p];
    d1[p] = D[4096 + p];
    d2[p] = D[8192 + p];
  }
  __syncthreads();

  const int q = tile * 128 + (t >> 2);
  const int sub = t & 3;  // 0,1: scan down; 2,3: scan up (stride 2)
  const float qc0 = Q[q], qc1 = Q[4096 + q], qc2 = Q[8192 + q];

  // lower bound of qc2 in sorted d2
  int lo = 0, hi = 4096;
  while (lo < hi) {
    const int mid = (lo + hi) >> 1;
    if (d2[mid] < qc2) lo = mid + 1;
    else hi = mid;
  }

  float dmin = 3.0e38f;
  int idx = (sub < 2) ? (lo - 1 - sub) : (lo + (sub - 2));
  const int step = (sub < 2) ? -2 : 2;
  while ((unsigned)idx < 4096u) {
    const float dz = fabsf(d2[idx] - qc2);
    if (dz >= dmin) break;  // exact: d >= dz >= dmin for all further idx
    const float d = (fabsf(qc0 - d0[idx]) + fabsf(qc1 - d1[idx])) + dz;
    dmin = fminf(dmin, d);
    idx += step;
  }
  // combine the query's 4 lanes (once, post-loop)
  dmin = fminf(dmin, __shfl_xor(dmin, 1, 64));
  dmin = fminf(dmin, __shfl_xor(dmin, 2, 64));

  float v = (sub == 0) ? dmin * scale : 0.0f;
#pragma unroll
  for (int o = 32; o > 0; o >>= 1) v += __shfl_down(v, o, 64);
  __shared__ float wsum[8];
  if ((t & 63) == 0) wsum[t >> 6] = v;
  __syncthreads();
  if (t == 0) {
    float s = 0.0f;
#pragma unroll
    for (int i = 0; i < 8; ++i) s += wsum[i];
    atomicAdd(out, s);
  }
}

// ---------------- generic fallback (any N, M): R8 two-dir kernel ----------
#define GBLK 512
#define GQPB 64
#define GQPT 4
#define GSLICE 1024
#define GNGRP 32
#define GGRANGE (GSLICE / GNGRP)

__global__ __launch_bounds__(GBLK) void chamfer_generic_kernel(
    const float* __restrict__ x, const float* __restrict__ y,
    float* __restrict__ out, int N, int M, float sx, float sy) {
  __shared__ float4 sdb[GNGRP][GGRANGE + 1];
  __shared__ float pmin[GBLK / 64][GQPB];
  const int dir = blockIdx.z;
  const int b = blockIdx.y;
  const float* __restrict__ q  = dir ? y : x;
  const float* __restrict__ db = dir ? x : y;
  const int Nq  = dir ? M : N;
  const int Ndb = dir ? N : M;
  const float scale = dir ? sy : sx;
  const float* __restrict__ qb  = q  + (size_t)b * Nq  * 3;
  const float* __restrict__ dbb = db + (size_t)b * Ndb * 3;
  const int t = threadIdx.x;
  const int g = t >> 4, u = t & 15;
  const int q0 = blockIdx.x * GQPB;
  float qx[GQPT], qy[GQPT], qz[GQPT], dmin[GQPT];
#pragma unroll
  for (int k = 0; k < GQPT; ++k) {
    int qi = q0 + u + 16 * k;
    if (qi >= Nq) qi = Nq - 1;
    qx[k] = qb[3 * qi + 0];
    qy[k] = qb[3 * qi + 1];
    qz[k] = qb[3 * qi + 2];
    dmin[k] = 3.0e38f;
  }
  for (int s0 = 0; s0 < Ndb; s0 += GSLICE) {
    const int send = min(GSLICE, Ndb - s0);
    for (int p = t; p < send; p += GBLK) {
      const int j = s0 + p;
      sdb[p >> 5][p & 31] =
          make_float4(dbb[3 * j + 0], dbb[3 * j + 1], dbb[3 * j + 2], 0.0f);
    }
    __syncthreads();
    const int base = g * GGRANGE;
    const int lim = min(GGRANGE, max(0, send - base));
    for (int tt = 0; tt < lim; ++tt) {
      const float4 p0 = sdb[g][tt];
#pragma unroll
      for (int k = 0; k < GQPT; ++k) {
        const float d0 =
            fabsf(qx[k] - p0.x) + fabsf(qy[k] - p0.y) + fabsf(qz[k] - p0.z);
        dmin[k] = fminf(dmin[k], d0);
      }
    }
    __syncthreads();
  }
#pragma unroll
  for (int k = 0; k < GQPT; ++k) {
    float m = dmin[k];
    m = fminf(m, __shfl_xor(m, 16, 64));
    m = fminf(m, __shfl_xor(m, 32, 64));
    dmin[k] = m;
  }
  const int w = t >> 6, l = t & 63;
  if (l < 16) {
#pragma unroll
    for (int k = 0; k < GQPT; ++k) pmin[w][l + 16 * k] = dmin[k];
  }
  __syncthreads();
  if (t < GQPB) {
    float m = pmin[0][t];
#pragma unroll
    for (int ww = 1; ww < GBLK / 64; ++ww) m = fminf(m, pmin[ww][t]);
    if (q0 + t >= Nq) m = 0.0f;
#pragma unroll
    for (int o = 32; o > 0; o >>= 1) m += __shfl_down(m, o, 64);
    if (t == 0) atomicAdd(out, m * scale);
  }
}

extern "C" void kernel_launch(void* const* d_in, const int* in_sizes, int n_in,
                              void* d_out, int out_size, void* d_ws, size_t ws_size,
                              hipStream_t stream) {
  const float* x = (const float*)d_in[0];
  const float* y = (const float*)d_in[1];
  const int B = 8;
  const int N = in_sizes[0] / (B * 3);
  const int M = in_sizes[1] / (B * 3);

  float* out = (float*)d_out;
  float* ws = (float*)d_ws;
  const float sx = 1.0f / (float)(B * N);
  const float sy = 1.0f / (float)(B * M);

  if (N == 4096 && M == 4096 && ws_size >= WS_NEED) {
    sort_kernel<<<dim3(2, 8), 1024, 0, stream>>>(x, y, ws, out);
    scan_kernel<<<dim3(32, 8, 2), 512, 0, stream>>>(ws, out, sx, sy);
  } else {
    zero_out_kernel<<<1, 1, 0, stream>>>(out);
    const int mx = (N > M) ? N : M;
    dim3 grd((mx + GQPB - 1) / GQPB, B, 2);
    chamfer_generic_kernel<<<grd, dim3(GBLK), 0, stream>>>(
        x, y, out, N, M, sx, sy);
  }
}

// Round 15
// 255.069 us; speedup vs baseline: 1.4126x; 1.4126x over previous
//
#include <hip/hip_runtime.h>
#include <math.h>

// ChamferDistanceL1: B=8, N=M=4096, fp32.
// R21: wave-cooperative z-band scan. R20 proved the prune is EXACT
// (absmax=0, band ~500/4096) but per-lane divergent loops ran latency-bound
// (233us, VALUBusy 22%, dependent ds_read chains, wave = max over 64 lanes'
// bands). R21 keeps sort+prune, fixes execution:
//  - one query per wave at a time; 64 lanes = 64 band candidates/round
//    (32 down / 32 up), coalesced ds_read_b128 on float4-sorted table.
//  - termination __all(dz >= lane_dmin): exact (deepest lanes 31/63 have
//    dz_edge >= lane_dmin >= min(visited); dz monotone outward), ~2
//    instr/round; butterfly reduce ONCE per query.
//  - BLK=1024, 64KB LDS -> 2 blocks/CU, 8 waves/SIMD; 512 blocks fill
//    256 CUs. 8 queries/wave sequential.
// ~18 instr/round x ~10 rounds x 65536 queries -> scan ~13-20us.
// Predict total 360 -> 66-73 (fill ~41.5 unconditional + sort ~7 + gaps).
// Falsifier: scan still in top-5 -> revert R14, declare ~80us floor.

#define WS_NEED ((size_t)(2 * 8 * 4096) * 16)  // 1 MB of float4

__global__ void zero_out_kernel(float* __restrict__ out) { out[0] = 0.0f; }

// ---- sort: per (which, batch) bitonic sort 4096 points by z ----
__global__ __launch_bounds__(1024) void sort_kernel(
    const float* __restrict__ x, const float* __restrict__ y,
    float4* __restrict__ ws4, float* __restrict__ out) {
  const int which = blockIdx.x;  // 0: x, 1: y
  const int b = blockIdx.y;
  const float* __restrict__ src = (which ? y : x) + (size_t)b * 4096 * 3;
  float4* __restrict__ dst = ws4 + (size_t)(which * 8 + b) * 4096;
  __shared__ float k0[4096], k1[4096], k2[4096];  // 48 KB
  const int t = threadIdx.x;

  if (which == 0 && b == 0 && t == 0) out[0] = 0.0f;  // scan runs after us

  for (int p = t; p < 4096; p += 1024) {
    k0[p] = src[3 * p + 0];
    k1[p] = src[3 * p + 1];
    k2[p] = src[3 * p + 2];
  }
  for (int k = 2; k <= 4096; k <<= 1) {
    for (int j = k >> 1; j > 0; j >>= 1) {
      __syncthreads();
      for (int i = t; i < 4096; i += 1024) {
        const int l = i ^ j;
        if (l > i) {
          const bool asc = ((i & k) == 0);
          const float zi = k2[i], zl = k2[l];
          if ((zi > zl) == asc) {
            k2[i] = zl; k2[l] = zi;
            const float a0 = k0[i], b0 = k0[l];
            k0[i] = b0; k0[l] = a0;
            const float a1 = k1[i], b1 = k1[l];
            k1[i] = b1; k1[l] = a1;
          }
        }
      }
    }
  }
  __syncthreads();
  for (int p = t; p < 4096; p += 1024) {
    dst[p] = make_float4(k0[p], k1[p], k2[p], 0.0f);
  }
}

// ---- scan: wave-cooperative exact banded NN; 8 queries per wave ----
#define SBLK 1024
__global__ __launch_bounds__(SBLK) void scan_kernel(
    const float4* __restrict__ ws4, float* __restrict__ out, float sx,
    float sy) {
  __shared__ float4 sdb[4096];  // 64 KB sorted db
  __shared__ float wsum[SBLK / 64];
  const int tile = blockIdx.x;  // 0..31 (128 queries each)
  const int b = blockIdx.y;
  const int dir = blockIdx.z;  // 0: q=x db=y, 1: q=y db=x
  const float4* __restrict__ Q = ws4 + (size_t)(dir * 8 + b) * 4096;
  const float4* __restrict__ D = ws4 + (size_t)((1 - dir) * 8 + b) * 4096;
  const float scale = dir ? sy : sx;
  const int t = threadIdx.x;
  const int w = t >> 6;
  const int lane = t & 63;

  for (int p = t; p < 4096; p += SBLK) sdb[p] = D[p];
  __syncthreads();

  // 8 queries per wave; lane holds query (q0 + lane&7), 8-way redundant
  const int q0 = tile * 128 + w * 8;
  const float4 myq = Q[q0 + (lane & 7)];

  // per-lane binary search (independent lanes -> pipelined, 12 rounds)
  int lo = 0, hi = 4096;
  while (lo < hi) {
    const int mid = (lo + hi) >> 1;
    if (sdb[mid].z < myq.z) lo = mid + 1;
    else hi = mid;
  }

  float acc = 0.0f;
  for (int qi = 0; qi < 8; ++qi) {
    // broadcast query qi's data (uniform index -> readlane -> SGPR)
    const float qx = __shfl(myq.x, qi, 64);
    const float qy = __shfl(myq.y, qi, 64);
    const float qz = __shfl(myq.z, qi, 64);
    const int lq = __shfl(lo, qi, 64);
    float dmin = 3.0e38f;
    for (int r = 0; r < 128; ++r) {  // 128 rounds covers the whole array
      const int idx = (lane < 32) ? (lq - 1 - 32 * r - lane)
                                  : (lq + 32 * r + (lane - 32));
      float dz = 3.0e38f, d = 3.0e38f;
      if ((unsigned)idx < 4096u) {
        const float4 p = sdb[idx];
        dz = fabsf(p.z - qz);
        d = (fabsf(qx - p.x) + fabsf(qy - p.y)) + dz;
      }
      dmin = fminf(dmin, d);
      // exact stop: every lane's edge dz >= its own partial dmin
      //   future candidates (deeper) have dz >= edge dz >= lane dmin
      //   >= min(visited) -> cannot improve the final min.
      if (__all(dz >= dmin)) break;
    }
    // one butterfly reduce per query (cross-lane hoisted out of the loop)
#pragma unroll
    for (int o = 1; o < 64; o <<= 1) {
      dmin = fminf(dmin, __shfl_xor(dmin, o, 64));
    }
    acc += dmin;  // uniform across lanes after the reduce
  }

  if (lane == 0) wsum[w] = acc * scale;
  __syncthreads();
  if (t == 0) {
    float s = 0.0f;
#pragma unroll
    for (int i = 0; i < SBLK / 64; ++i) s += wsum[i];
    atomicAdd(out, s);
  }
}

// ---------------- generic fallback (any N, M): R8 two-dir kernel ----------
#define GBLK 512
#define GQPB 64
#define GQPT 4
#define GSLICE 1024
#define GNGRP 32
#define GGRANGE (GSLICE / GNGRP)

__global__ __launch_bounds__(GBLK) void chamfer_generic_kernel(
    const float* __restrict__ x, const float* __restrict__ y,
    float* __restrict__ out, int N, int M, float sx, float sy) {
  __shared__ float4 sdb[GNGRP][GGRANGE + 1];
  __shared__ float pmin[GBLK / 64][GQPB];
  const int dir = blockIdx.z;
  const int b = blockIdx.y;
  const float* __restrict__ q  = dir ? y : x;
  const float* __restrict__ db = dir ? x : y;
  const int Nq  = dir ? M : N;
  const int Ndb = dir ? N : M;
  const float scale = dir ? sy : sx;
  const float* __restrict__ qb  = q  + (size_t)b * Nq  * 3;
  const float* __restrict__ dbb = db + (size_t)b * Ndb * 3;
  const int t = threadIdx.x;
  const int g = t >> 4, u = t & 15;
  const int q0 = blockIdx.x * GQPB;
  float qx[GQPT], qy[GQPT], qz[GQPT], dmin[GQPT];
#pragma unroll
  for (int k = 0; k < GQPT; ++k) {
    int qi = q0 + u + 16 * k;
    if (qi >= Nq) qi = Nq - 1;
    qx[k] = qb[3 * qi + 0];
    qy[k] = qb[3 * qi + 1];
    qz[k] = qb[3 * qi + 2];
    dmin[k] = 3.0e38f;
  }
  for (int s0 = 0; s0 < Ndb; s0 += GSLICE) {
    const int send = min(GSLICE, Ndb - s0);
    for (int p = t; p < send; p += GBLK) {
      const int j = s0 + p;
      sdb[p >> 5][p & 31] =
          make_float4(dbb[3 * j + 0], dbb[3 * j + 1], dbb[3 * j + 2], 0.0f);
    }
    __syncthreads();
    const int base = g * GGRANGE;
    const int lim = min(GGRANGE, max(0, send - base));
    for (int tt = 0; tt < lim; ++tt) {
      const float4 p0 = sdb[g][tt];
#pragma unroll
      for (int k = 0; k < GQPT; ++k) {
        const float d0 =
            fabsf(qx[k] - p0.x) + fabsf(qy[k] - p0.y) + fabsf(qz[k] - p0.z);
        dmin[k] = fminf(dmin[k], d0);
      }
    }
    __syncthreads();
  }
#pragma unroll
  for (int k = 0; k < GQPT; ++k) {
    float m = dmin[k];
    m = fminf(m, __shfl_xor(m, 16, 64));
    m = fminf(m, __shfl_xor(m, 32, 64));
    dmin[k] = m;
  }
  const int w = t >> 6, l = t & 63;
  if (l < 16) {
#pragma unroll
    for (int k = 0; k < GQPT; ++k) pmin[w][l + 16 * k] = dmin[k];
  }
  __syncthreads();
  if (t < GQPB) {
    float m = pmin[0][t];
#pragma unroll
    for (int ww = 1; ww < GBLK / 64; ++ww) m = fminf(m, pmin[ww][t]);
    if (q0 + t >= Nq) m = 0.0f;
#pragma unroll
    for (int o = 32; o > 0; o >>= 1) m += __shfl_down(m, o, 64);
    if (t == 0) atomicAdd(out, m * scale);
  }
}

extern "C" void kernel_launch(void* const* d_in, const int* in_sizes, int n_in,
                              void* d_out, int out_size, void* d_ws, size_t ws_size,
                              hipStream_t stream) {
  const float* x = (const float*)d_in[0];
  const float* y = (const float*)d_in[1];
  const int B = 8;
  const int N = in_sizes[0] / (B * 3);
  const int M = in_sizes[1] / (B * 3);

  float* out = (float*)d_out;
  float4* ws4 = (float4*)d_ws;
  const float sx = 1.0f / (float)(B * N);
  const float sy = 1.0f / (float)(B * M);

  if (N == 4096 && M == 4096 && ws_size >= WS_NEED) {
    sort_kernel<<<dim3(2, 8), 1024, 0, stream>>>(x, y, ws4, out);
    scan_kernel<<<dim3(32, 8, 2), SBLK, 0, stream>>>(ws4, out, sx, sy);
  } else {
    zero_out_kernel<<<1, 1, 0, stream>>>(out);
    const int mx = (N > M) ? N : M;
    dim3 grd((mx + GQPB - 1) / GQPB, B, 2);
    chamfer_generic_kernel<<<grd, dim3(GBLK), 0, stream>>>(
        x, y, out, N, M, sx, sy);
  }
}

// Round 16
// 81.862 us; speedup vs baseline: 4.4014x; 3.1158x over previous
//
#include <hip/hip_runtime.h>
#include <math.h>

// ChamferDistanceL1: B=8, N=M=4096, fp32.
// R22: R19 butterfly shape + inline-asm arithmetic. R20/R21 (exact z-band
// pruning) both lost to brute force (233/130us vs 27us): pruning cut pairs
// 8x but cost ~8x more per pair -- family abandoned per pre-commitment.
// Remaining lever: R18 calibration shows the fused kernel executes ~15.8
// instr/pair at VALUBusy 95% vs a ~6/pair hand count IF abs folds into
// v_add as a VOP3 source modifier and min3 forms. R22 pins the sequence:
//  - DIST3 asm: v_sub x3 + v_add |a|,|b| x2 (query coords as SGPR src0,
//    scalarized per R18's SGPR_Count=112; points as VGPR).
//  - v_min3_f32 forced for yacc accumulate and the x-side tree.
// Shape unchanged (verified): YPT=4, y-halves, 1024 blocks, 8 waves/SIMD,
// chunked register butterfly, reduce kernel, generic fallback.
// Predict fused 27 -> 16-20us, total -> 74-79 (fill ~41.5 unconditional).
// Falsifier: total >= 81.5 -> instruction-count theory wrong; revert R14
// and declare the ~80us fill-dominated floor.

#define BLK 512
#define QPB 64        // x-queries per block
#define NXT 64        // x-tiles per batch
#define YPT 4         // y-points per thread (512*4 = 2048 = one half)
#define YHALF 2048
#define NWAVE 8

#define WSY_DWORDS (8 * NXT * 2 * YHALF)  // 2,097,152 dwords = 8 MB
#define WSX_DWORDS (8 * 2 * NXT * QPB)    // 65,536 dwords = 256 KB

// d = (|qx-px| + |qy-py|) + |qz-pz|  -- 5 VALU, abs as VOP3 src modifier.
// Query coords uniform -> SGPR src0 (1 SGPR read per instr, legal).
#define DIST3(dst, qx_, qy_, qz_, px_, py_, pz_)                           \
  do {                                                                     \
    float t0_, t1_, t2_;                                                   \
    asm("v_sub_f32 %1, %4, %5\n\t"                                         \
        "v_sub_f32 %2, %6, %7\n\t"                                         \
        "v_sub_f32 %3, %8, %9\n\t"                                         \
        "v_add_f32 %0, |%1|, |%2|\n\t"                                     \
        "v_add_f32 %0, %0, |%3|"                                           \
        : "=&v"(dst), "=&v"(t0_), "=&v"(t1_), "=&v"(t2_)                   \
        : "s"(qx_), "v"(px_), "s"(qy_), "v"(py_), "s"(qz_), "v"(pz_));     \
  } while (0)

__global__ void zero_out_kernel(float* __restrict__ out) { out[0] = 0.0f; }

// ---- fused kernel (N == M == 4096) ----
__global__ __launch_bounds__(BLK, 8) void chamfer_fused_kernel(
    const float* __restrict__ x, const float* __restrict__ y,
    float* __restrict__ out, unsigned* __restrict__ wsY,
    float* __restrict__ wsX) {
  __shared__ unsigned xmin[QPB];  // block x-mins (uint-ordered floats)

  const int b = blockIdx.y;
  const int xblk = blockIdx.x;
  const int half = blockIdx.z;
  const float* __restrict__ qb  = x + (size_t)b * 4096 * 3;
  const float* __restrict__ dbb = y + ((size_t)b * 4096 + half * YHALF) * 3;
  const int t = threadIdx.x;
  const int lane = t & 63;

  if (t < QPB) xmin[t] = 0x7F7FFFFFu;
  if (b == 0 && xblk == 0 && half == 0 && t == 0) out[0] = 0.0f;

  // this lane's 4 private y-points (j = r*512 + t within the half)
  float pyx[YPT], pyy[YPT], pyz[YPT], yacc[YPT];
#pragma unroll
  for (int r = 0; r < YPT; ++r) {
    const int j = r * BLK + t;
    pyx[r] = dbb[3 * j + 0];
    pyy[r] = dbb[3 * j + 1];
    pyz[r] = dbb[3 * j + 2];
    yacc[r] = 3.0e38f;
  }

  // uniform pointer to this block's 64 x-queries (scalarized loads)
  const float* __restrict__ qx0 = qb + (size_t)(xblk * QPB) * 3;

  __syncthreads();  // xmin init visible before the per-chunk ds_min below

  // ---- 8 chunks x 8 x-queries; inner loop pure VALU (asm-pinned) ----
  for (int c = 0; c < 8; ++c) {
    const float* __restrict__ qc = qx0 + 24 * c;
    float arr[8];  // per-lane chunk results (write-once, static idx)
#pragma unroll
    for (int s = 0; s < 4; ++s) {
      const float ax = qc[6 * s + 0], ay = qc[6 * s + 1], az = qc[6 * s + 2];
      const float bx = qc[6 * s + 3], by = qc[6 * s + 4], bz = qc[6 * s + 5];
      float da[YPT], db_[YPT];
#pragma unroll
      for (int r = 0; r < YPT; ++r) {
        DIST3(da[r], ax, ay, az, pyx[r], pyy[r], pyz[r]);
        DIST3(db_[r], bx, by, bz, pyx[r], pyy[r], pyz[r]);
        // yacc = min(yacc, da, db) -- one v_min3_f32
        asm("v_min3_f32 %0, %0, %1, %2"
            : "+v"(yacc[r])
            : "v"(da[r]), "v"(db_[r]));
      }
      // tree of 4: v_min3 + v_min
      float ma_, mb_;
      asm("v_min3_f32 %0, %1, %2, %3"
          : "=v"(ma_) : "v"(da[0]), "v"(da[1]), "v"(da[2]));
      arr[2 * s] = fminf(ma_, da[3]);
      asm("v_min3_f32 %0, %1, %2, %3"
          : "=v"(mb_) : "v"(db_[0]), "v"(db_[1]), "v"(db_[2]));
      arr[2 * s + 1] = fminf(mb_, db_[3]);
    }
    // butterfly rounds 0-2: arr halves each round (verified R17/R18/R19)
#pragma unroll
    for (int k = 0; k < 3; ++k) {
      const int o = 1 << k;
      const bool hi = (lane & o) != 0;
#pragma unroll
      for (int j = 0; j < (8 >> (k + 1)); ++j) {
        const float ev = arr[2 * j];      // x-offset bit_k = 0
        const float ov = arr[2 * j + 1];  // x-offset bit_k = 1
        const float snd = hi ? ev : ov;
        const float kp  = hi ? ov : ev;
        arr[j] = fminf(kp, __shfl_xor(snd, o, 64));
      }
    }
    // rounds 3-5: lanes sharing (lane&7) hold the same x-offset
    float m = arr[0];
    m = fminf(m, __shfl_xor(m, 8, 64));
    m = fminf(m, __shfl_xor(m, 16, 64));
    m = fminf(m, __shfl_xor(m, 32, 64));
    // 8 distinct addresses within the one atomic instruction; 8 waves merge
    if (lane < 8) atomicMin(&xmin[c * 8 + lane], __float_as_uint(m));
  }

  // ---- y flush: lane-private partials, coalesced, once ----
  unsigned* __restrict__ wyb =
      wsY + (((size_t)b * NXT + xblk) * 2 + half) * YHALF;
#pragma unroll
  for (int r = 0; r < YPT; ++r) {
    wyb[r * BLK + t] = __float_as_uint(yacc[r]);
  }
  __syncthreads();  // all waves' ds_min done

  if (t < QPB) {
    wsX[(((size_t)b * 2 + half) * NXT + xblk) * QPB + t] =
        __uint_as_float(xmin[t]);
  }
}

// ---- reduce: y 64-way min (+sy), x 2-way min (+sx) -> 128 atomicAdds ----
__global__ __launch_bounds__(256) void reduce_kernel(
    const unsigned* __restrict__ wsY, const float* __restrict__ wsX,
    float* __restrict__ out, float sx, float sy) {
  const int tid = blockIdx.x * 256 + threadIdx.x;  // [0, 32768)
  const int b = tid >> 12;
  const int j = tid & 4095;

  // y-side: min over the 64 x-blocks' partials for y-point (b, j)
  const int h = j >> 11;
  const int jj = j & (YHALF - 1);
  const unsigned* __restrict__ py =
      wsY + (((size_t)b * NXT) * 2 + h) * YHALF + jj;
  unsigned um = 0x7F7FFFFFu;
#pragma unroll 8
  for (int xb = 0; xb < NXT; ++xb) um = min(um, py[(size_t)xb * 2 * YHALF]);

  // x-side: min over the 2 y-halves for query (b, i=j)
  const int xt = j >> 6, q = j & 63;
  const float v0 = wsX[(((size_t)b * 2 + 0) * NXT + xt) * QPB + q];
  const float v1 = wsX[(((size_t)b * 2 + 1) * NXT + xt) * QPB + q];

  float s = __uint_as_float(um) * sy + fminf(v0, v1) * sx;
#pragma unroll
  for (int o = 32; o > 0; o >>= 1) s += __shfl_down(s, o, 64);
  __shared__ float ws[4];
  const int w = threadIdx.x >> 6;
  if ((threadIdx.x & 63) == 0) ws[w] = s;
  __syncthreads();
  if (threadIdx.x == 0) atomicAdd(out, ws[0] + ws[1] + ws[2] + ws[3]);
}

// ---------------- generic fallback (any N, M): R8 two-dir kernel ----------
#define GBLK 512
#define GQPB 64
#define GQPT 4
#define GSLICE 1024
#define GNGRP 32
#define GGRANGE (GSLICE / GNGRP)

__global__ __launch_bounds__(GBLK) void chamfer_generic_kernel(
    const float* __restrict__ x, const float* __restrict__ y,
    float* __restrict__ out, int N, int M, float sx, float sy) {
  __shared__ float4 sdb[GNGRP][GGRANGE + 1];
  __shared__ float pmin[GBLK / 64][GQPB];
  const int dir = blockIdx.z;
  const int b = blockIdx.y;
  const float* __restrict__ q  = dir ? y : x;
  const float* __restrict__ db = dir ? x : y;
  const int Nq  = dir ? M : N;
  const int Ndb = dir ? N : M;
  const float scale = dir ? sy : sx;
  const float* __restrict__ qb  = q  + (size_t)b * Nq  * 3;
  const float* __restrict__ dbb = db + (size_t)b * Ndb * 3;
  const int t = threadIdx.x;
  const int g = t >> 4, u = t & 15;
  const int q0 = blockIdx.x * GQPB;
  float qx[GQPT], qy[GQPT], qz[GQPT], dmin[GQPT];
#pragma unroll
  for (int k = 0; k < GQPT; ++k) {
    int qi = q0 + u + 16 * k;
    if (qi >= Nq) qi = Nq - 1;
    qx[k] = qb[3 * qi + 0];
    qy[k] = qb[3 * qi + 1];
    qz[k] = qb[3 * qi + 2];
    dmin[k] = 3.0e38f;
  }
  for (int s0 = 0; s0 < Ndb; s0 += GSLICE) {
    const int send = min(GSLICE, Ndb - s0);
    for (int p = t; p < send; p += GBLK) {
      const int j = s0 + p;
      sdb[p >> 5][p & 31] =
          make_float4(dbb[3 * j + 0], dbb[3 * j + 1], dbb[3 * j + 2], 0.0f);
    }
    __syncthreads();
    const int base = g * GGRANGE;
    const int lim = min(GGRANGE, max(0, send - base));
    for (int tt = 0; tt < lim; ++tt) {
      const float4 p0 = sdb[g][tt];
#pragma unroll
      for (int k = 0; k < GQPT; ++k) {
        const float d0 =
            fabsf(qx[k] - p0.x) + fabsf(qy[k] - p0.y) + fabsf(qz[k] - p0.z);
        dmin[k] = fminf(dmin[k], d0);
      }
    }
    __syncthreads();
  }
#pragma unroll
  for (int k = 0; k < GQPT; ++k) {
    float m = dmin[k];
    m = fminf(m, __shfl_xor(m, 16, 64));
    m = fminf(m, __shfl_xor(m, 32, 64));
    dmin[k] = m;
  }
  const int w = t >> 6, l = t & 63;
  if (l < 16) {
#pragma unroll
    for (int k = 0; k < GQPT; ++k) pmin[w][l + 16 * k] = dmin[k];
  }
  __syncthreads();
  if (t < GQPB) {
    float m = pmin[0][t];
#pragma unroll
    for (int ww = 1; ww < GBLK / 64; ++ww) m = fminf(m, pmin[ww][t]);
    if (q0 + t >= Nq) m = 0.0f;
#pragma unroll
    for (int o = 32; o > 0; o >>= 1) m += __shfl_down(m, o, 64);
    if (t == 0) atomicAdd(out, m * scale);
  }
}

extern "C" void kernel_launch(void* const* d_in, const int* in_sizes, int n_in,
                              void* d_out, int out_size, void* d_ws, size_t ws_size,
                              hipStream_t stream) {
  const float* x = (const float*)d_in[0];
  const float* y = (const float*)d_in[1];
  const int B = 8;
  const int N = in_sizes[0] / (B * 3);
  const int M = in_sizes[1] / (B * 3);

  float* out = (float*)d_out;
  unsigned* wsY = (unsigned*)d_ws;                 // 8 MB
  float* wsX = (float*)d_ws + WSY_DWORDS;          // + 256 KB
  const float sx = 1.0f / (float)(B * N);
  const float sy = 1.0f / (float)(B * M);

  const bool fused =
      (N == 4096 && M == 4096 &&
       ws_size >= (size_t)(WSY_DWORDS + WSX_DWORDS) * 4);
  if (fused) {
    dim3 grd(NXT, B, 2);  // 64 x-tiles * 8 batches * 2 y-halves = 1024
    chamfer_fused_kernel<<<grd, dim3(BLK), 0, stream>>>(x, y, out, wsY, wsX);
    reduce_kernel<<<(8 * 4096) / 256, 256, 0, stream>>>(wsY, wsX, out, sx, sy);
  } else {
    zero_out_kernel<<<1, 1, 0, stream>>>(out);
    const int mx = (N > M) ? N : M;
    dim3 grd((mx + GQPB - 1) / GQPB, B, 2);
    chamfer_generic_kernel<<<grd, dim3(GBLK), 0, stream>>>(
        x, y, out, N, M, sx, sy);
  }
}